// Round 2
// 249.941 us; speedup vs baseline: 1.0839x; 1.0839x over previous
//
#include <hip/hip_runtime.h>
#include <hip/hip_bf16.h>

typedef __hip_bfloat16 bf16;
// match the builtin's own return type (__fp16 ext_vector(2)) exactly
using hf2 = decltype(__builtin_amdgcn_cvt_pkrtz(0.f, 0.f));

__device__ __forceinline__ float b2f(bf16 x) { return __bfloat162float(x); }

// ---------------------------------------------------------------------------
// Problem constants
// ---------------------------------------------------------------------------
#define BB   2
#define FF   16
#define HH   64
#define WW   64
#define CC   16     // in/out channels == MID
#define NIMG (BB*FF)        // 32
#define PIX  (HH*WW)        // 4096
#define IMGSZ (PIX*CC)      // 65536 elements per image (channel-last)

// scale(=1/sqrt(2)) * log2(e): folded into staged Wq; softmax uses raw v_exp_f32
#define QSCALE_LOG2E 1.0201394f

// ---- packed f16x2 helpers (v_cvt_pkrtz_f16_f32 / v_dot2_f32_f16) ----
__device__ __forceinline__ unsigned pkh2(float a, float b) {
    union { hf2 h; unsigned u; } x;
    x.h = __builtin_amdgcn_cvt_pkrtz(a, b);
    return x.u;
}
__device__ __forceinline__ float fdot2u(unsigned a, unsigned b, float c) {
    union { unsigned u; hf2 h; } A, B;
    A.u = a; B.u = b;
    return __builtin_amdgcn_fdot2(A.h, B.h, c, false);
}

// ---- 16-element bf16 I/O (intermediates A/R) ----
__device__ __forceinline__ void ld16bf(const bf16* p, float* x) {
    const uint4* p4 = reinterpret_cast<const uint4*>(p);
    uint4 u0 = p4[0], u1 = p4[1];
    unsigned uu[8] = {u0.x, u0.y, u0.z, u0.w, u1.x, u1.y, u1.z, u1.w};
    #pragma unroll
    for (int k = 0; k < 8; ++k) {
        union { unsigned u; float f; } lo, hi;
        lo.u = uu[k] << 16;
        hi.u = uu[k] & 0xffff0000u;
        x[2 * k] = lo.f;
        x[2 * k + 1] = hi.f;
    }
}
__device__ __forceinline__ void st16bf(bf16* p, const float* x) {
    union { bf16 h[16]; uint4 u[2]; } o;
    #pragma unroll
    for (int k = 0; k < 16; ++k) o.h[k] = __float2bfloat16(x[k]);
    uint4* p4 = reinterpret_cast<uint4*>(p);
    p4[0] = o.u[0];
    p4[1] = o.u[1];
}

// ---- 16-element fp32 I/O (global inputs/outputs) ----
__device__ __forceinline__ void ld16f(const float* p, float* x) {
    const float4* p4 = reinterpret_cast<const float4*>(p);
    #pragma unroll
    for (int q = 0; q < 4; ++q) {
        float4 v = p4[q];
        x[4 * q] = v.x; x[4 * q + 1] = v.y; x[4 * q + 2] = v.z; x[4 * q + 3] = v.w;
    }
}
__device__ __forceinline__ void st16f(float* p, const float* x) {
    float4* p4 = reinterpret_cast<float4*>(p);
    #pragma unroll
    for (int q = 0; q < 4; ++q)
        p4[q] = make_float4(x[4 * q], x[4 * q + 1], x[4 * q + 2], x[4 * q + 3]);
}

__device__ __forceinline__ unsigned packbf2(float a, float b) {
    union { bf16 h[2]; unsigned u; } pk;
    pk.h[0] = __float2bfloat16(a);
    pk.h[1] = __float2bfloat16(b);
    return pk.u;
}

// ---------------------------------------------------------------------------
// Kernel 1: conv stem on hidden (->A) and ref (->R, + fused emb-MLP).
// ---------------------------------------------------------------------------
__global__ __launch_bounds__(256) void conv_in_kernel(
    const float* __restrict__ hid, const float* __restrict__ ref,
    const float* __restrict__ cw, const float* __restrict__ cb,
    const float* __restrict__ emb,
    const float* __restrict__ e1w, const float* __restrict__ e1b,
    const float* __restrict__ e2w, const float* __restrict__ e2b,
    bf16* __restrict__ A, bf16* __restrict__ R)
{
    __shared__ float wl[9 * 256];   // [tap][ic][oc]
    __shared__ float bl[16];
    __shared__ float hl[16];
    __shared__ float el[16];
    int t = threadIdx.x;
    {
        int ic = t >> 4, oc = t & 15;
        #pragma unroll
        for (int k = 0; k < 9; ++k)
            wl[k * 256 + t] = cw[(oc * 16 + ic) * 9 + k];
    }
    if (t < 16) bl[t] = cb[t];

    int gid  = blockIdx.x * 256 + t;       // 0 .. 2*NIMG*PIX-1
    int wi   = gid & 63;
    int hi   = (gid >> 6) & 63;
    int img2 = gid >> 12;                  // uniform per block (16 blocks/img)
    int isref = img2 >> 5;
    int img  = img2 & 31;
    int bi   = img >> 4;

    if (isref) {        // block-uniform branch: barriers inside are safe
        if (t < 16) {
            float acc = e1b[t];
            const float* er = emb + bi * 512;
            const float* wr = e1w + t * 512;
            for (int k = 0; k < 512; ++k) acc = fmaf(er[k], wr[k], acc);
            hl[t] = acc / (1.f + __expf(-acc));   // silu
        }
        __syncthreads();
        if (t < 16) {
            float acc = e2b[t];
            #pragma unroll
            for (int k = 0; k < 16; ++k) acc = fmaf(hl[k], e2w[t * 16 + k], acc);
            el[t] = acc;
        }
    }
    __syncthreads();

    const float* inp = (isref ? ref : hid) + (size_t)img * IMGSZ;
    float acc[16];
    #pragma unroll
    for (int oc = 0; oc < 16; ++oc)
        acc[oc] = bl[oc] + (isref ? el[oc] : 0.f);

    for (int ky = 0; ky < 3; ++ky) {
        int y = hi + ky - 1;
        if ((unsigned)y >= 64u) continue;
        for (int kx = 0; kx < 3; ++kx) {
            int x = wi + kx - 1;
            if ((unsigned)x >= 64u) continue;
            float xv[16];
            ld16f(inp + (((y << 6) + x) << 4), xv);
            const float* wt = &wl[(ky * 3 + kx) * 256];
            #pragma unroll
            for (int ic = 0; ic < 16; ++ic) {
                #pragma unroll
                for (int oc = 0; oc < 16; ++oc)
                    acc[oc] = fmaf(xv[ic], wt[ic * 16 + oc], acc[oc]);
            }
        }
    }
    bf16* op = (isref ? R : A) + ((size_t)(img * PIX + (hi << 6) + wi) << 4);
    st16bf(op, acc);
}

// ---------------------------------------------------------------------------
// Attention stage. 256 threads; TPT = 256/(SEQPB*S) threads per token (1 or 2).
// Sequence s: tokens j<S/2 from A, j>=S/2 from R.
//   token j elem offset = (s/d2)*str1 + (s%d2)*str2 + j*tokStride
// Output (first S/2 tokens) written in place into A (bf16).
//
// v0.51 layout:
//  - k and q packed f16x2 per head (score = one v_dot2_f32_f16, Wq pre-scaled
//    by scale*log2e so softmax is raw v_exp_f32 in the exp2 domain)
//  - v packed bf16x2 (2-instr shift unpack)
//  - QKV projection via fdot2 against f16x2-packed staged weights
//  - qoL removed: q lives in qL (KROW=10 uint rows, conflict-free phase-2
//    reads: banks 8*qg + 10*qq + hd tile all 32); f32 output rows (stride 20)
//    are overlaid on kU after the mid-phase-2 barrier (sizes match exactly:
//    SEQPB*S*10 uints == SEQPB*HS*20 floats).  Y-stage LDS 35->28.5 KB.
// ---------------------------------------------------------------------------
template<int S, int SEQPB, int MINW>
__global__ __launch_bounds__(256, MINW) void attn_kernel(
    bf16* __restrict__ A, const bf16* __restrict__ R,
    int d2, int str1, int str2, int tokStride,
    const float* __restrict__ wq, const float* __restrict__ wk,
    const float* __restrict__ wv, const float* __restrict__ wo,
    const float* __restrict__ bo, const float* __restrict__ gw,
    const float* __restrict__ bw)
{
    constexpr int HS  = S / 2;             // queries per sequence
    constexpr int KQ  = S / 2;             // keys per phase-2 thread (parity)
    constexpr int TPT = 256 / (SEQPB * S); // threads per token: 1 or 2
    constexpr int NDIM = 16 / TPT;         // qkv dims per phase-1 thread
    constexpr int ITEMS = 256 / SEQPB;     // phase-2 threads per sequence
    constexpr int NQG = ITEMS / 16;        // query groups per sequence
    constexpr int QB  = HS / NQG;          // queries per phase-2 thread
    constexpr int KROW = 10;               // k/v/q token row stride (uints)
    constexpr int QROW = 20;               // o row stride (floats)
    constexpr int LSQ = (SEQPB == 1) ? 0 : ((SEQPB == 2) ? 1 : 2);
    constexpr int NW3 = SEQPB * HS * 8 / 256;  // phase-3 reps

    __shared__ float wolT[256];
    __shared__ unsigned wq2L[128], wk2L[128], wv2L[128];   // f16x2-packed rows
    __shared__ float bol[16], gl[16], blw[16];
    __shared__ __align__(16) unsigned kU[SEQPB * S * KROW];   // k f16x2; o (f32, stride 20) after barrier
    __shared__ __align__(16) unsigned vU[SEQPB * S * KROW];   // v bf16x2
    __shared__ __align__(16) unsigned qL[SEQPB * HS * KROW];  // q f16x2 (scaled)
    __shared__ int bases[SEQPB];

    int t = threadIdx.x;
    wolT[(t & 15) * 16 + (t >> 4)] = wo[t];   // transposed: [d][c]
    if (t < 128) {
        // pack weight rows [d][c] -> [d][c/2] f16x2; wq pre-scaled
        float2 qw = reinterpret_cast<const float2*>(wq)[t];
        float2 kw = reinterpret_cast<const float2*>(wk)[t];
        float2 vw = reinterpret_cast<const float2*>(wv)[t];
        wq2L[t] = pkh2(qw.x * QSCALE_LOG2E, qw.y * QSCALE_LOG2E);
        wk2L[t] = pkh2(kw.x, kw.y);
        wv2L[t] = pkh2(vw.x, vw.y);
    }
    if (t < 16) { bol[t] = bo[t]; gl[t] = gw[t]; blw[t] = bw[t]; }
    if (t < SEQPB) {
        int seq = blockIdx.x * SEQPB + t;
        bases[t] = (seq / d2) * str1 + (seq % d2) * str2;
    }
    __syncthreads();

    // ---- phase 1: token load, +posembed, LayerNorm, QKV (fdot2) -> LDS ----
    {
        int tokIdx = (TPT == 2) ? (t >> 1) : t;
        int db     = (TPT == 2) ? ((t & 1) * 8) : 0;
        int sq = tokIdx & (SEQPB - 1);     // sq fastest: adjacent lanes coalesce
        int i  = tokIdx >> LSQ;
        const bf16* src = (i < HS)
            ? (A + bases[sq] + (size_t)i * tokStride)
            : (R + bases[sq] + (size_t)(i - HS) * tokStride);
        float x[16];
        ld16bf(src, x);
        const float om[8] = {1.f, 0.31622776601683794f, 0.1f, 0.031622776601683794f,
                             0.01f, 0.0031622776601683794f, 0.001f, 0.00031622776601683794f};
        float fi = (float)i;
        #pragma unroll
        for (int k = 0; k < 8; ++k) {
            float sv, cv;
            __sincosf(fi * om[k], &sv, &cv);
            x[k]     += sv;
            x[k + 8] += cv;
        }
        float m = 0.f;
        #pragma unroll
        for (int c = 0; c < 16; ++c) m += x[c];
        m *= (1.f / 16.f);
        float var = 0.f;
        #pragma unroll
        for (int c = 0; c < 16; ++c) { float d = x[c] - m; var = fmaf(d, d, var); }
        var *= (1.f / 16.f);
        float rs = rsqrtf(var + 1e-5f);
        float xn[16];
        #pragma unroll
        for (int c = 0; c < 16; ++c) xn[c] = (x[c] - m) * rs * gl[c] + blw[c];

        // pack normalized token once; all three projections become dot2 chains
        unsigned xp[8];
        #pragma unroll
        for (int c2 = 0; c2 < 8; ++c2) xp[c2] = pkh2(xn[2 * c2], xn[2 * c2 + 1]);

        float qv[NDIM], kv[NDIM], vv[NDIM];
        #pragma unroll
        for (int dd = 0; dd < NDIM; ++dd) {
            int d = db + dd;
            float aq = 0.f, ak = 0.f, av = 0.f;
            #pragma unroll
            for (int c2 = 0; c2 < 8; ++c2) {
                aq = fdot2u(xp[c2], wq2L[d * 8 + c2], aq);
                ak = fdot2u(xp[c2], wk2L[d * 8 + c2], ak);
                av = fdot2u(xp[c2], wv2L[d * 8 + c2], av);
            }
            qv[dd] = aq; kv[dd] = ak; vv[dd] = av;
        }
        int row = (sq * S + i) * KROW + (db >> 1);   // uint index, even
        uint2* kr = reinterpret_cast<uint2*>(&kU[row]);
        uint2* vr = reinterpret_cast<uint2*>(&vU[row]);
        #pragma unroll
        for (int e = 0; e < NDIM / 4; ++e) {
            kr[e] = make_uint2(pkh2(kv[4 * e], kv[4 * e + 1]),
                               pkh2(kv[4 * e + 2], kv[4 * e + 3]));
            vr[e] = make_uint2(packbf2(vv[4 * e], vv[4 * e + 1]),
                               packbf2(vv[4 * e + 2], vv[4 * e + 3]));
        }
        if (i < HS) {
            uint2* qr = reinterpret_cast<uint2*>(&qL[(sq * HS + i) * KROW + (db >> 1)]);
            #pragma unroll
            for (int e = 0; e < NDIM / 4; ++e)
                qr[e] = make_uint2(pkh2(qv[4 * e], qv[4 * e + 1]),
                                   pkh2(qv[4 * e + 2], qv[4 * e + 3]));
        }
    }
    __syncthreads();

    // ---- phase 2: single-pass softmax (exp2 domain), parity key split ----
    int sq2 = t / ITEMS;
    int r   = t % ITEMS;
    int qg  = r >> 4;          // query group (QB queries)
    int hd  = (r >> 1) & 7;    // head
    int half = r & 1;          // key parity
    float* oL = reinterpret_cast<float*>(kU);   // overlay after barrier
    {
        unsigned q2[QB];
        float l[QB], a0[QB], a1[QB];
        #pragma unroll
        for (int qq = 0; qq < QB; ++qq) {
            q2[qq] = qL[(sq2 * HS + qg * QB + qq) * KROW + hd];  // scaled f16x2
            l[qq] = 0.f; a0[qq] = 0.f; a1[qq] = 0.f;
        }
        const unsigned* kp = &kU[(sq2 * S + half) * KROW + hd];
        const unsigned* vp = &vU[(sq2 * S + half) * KROW + hd];
        #pragma unroll 8
        for (int jj = 0; jj < KQ; ++jj) {            // key j = 2*jj + half
            unsigned ku = kp[jj * 2 * KROW];
            unsigned vu = vp[jj * 2 * KROW];
            union { unsigned u; float f; } v0, v1;
            v0.u = vu << 16; v1.u = vu & 0xffff0000u;
            #pragma unroll
            for (int qq = 0; qq < QB; ++qq) {
                float s = fdot2u(q2[qq], ku, 0.f);   // q0*k0 + q1*k1, one instr
                float p = __builtin_amdgcn_exp2f(s);
                l[qq] += p;
                a0[qq] = fmaf(p, v0.f, a0[qq]);
                a1[qq] = fmaf(p, v1.f, a1[qq]);
            }
        }
        #pragma unroll
        for (int qq = 0; qq < QB; ++qq) {
            l[qq]  += __shfl_xor(l[qq], 1);
            a0[qq] += __shfl_xor(a0[qq], 1);
            a1[qq] += __shfl_xor(a1[qq], 1);
        }
        __syncthreads();   // all k/q reads done in every thread; kU reusable as oL
        if (half == 0) {
            #pragma unroll
            for (int qq = 0; qq < QB; ++qq) {
                float inv = 1.f / l[qq];
                *reinterpret_cast<float2*>(
                    &oL[(sq2 * HS + qg * QB + qq) * QROW + 2 * hd]) =
                    make_float2(a0[qq] * inv, a1[qq] * inv);
            }
        }
    }
    __syncthreads();

    // ---- phase 3: out-proj, in-place bf16x2 write; sq fastest for lines ----
    #pragma unroll
    for (int rep = 0; rep < NW3; ++rep) {
        int idx = t + rep * 256;          // < SEQPB*HS*8
        int cp  = idx & 7;                // channel pair
        int g   = idx >> 3;
        int sq3 = g & (SEQPB - 1);
        int tok = g >> LSQ;
        const float* orow = &oL[(sq3 * HS + tok) * QROW];
        float acc0 = bol[2 * cp], acc1 = bol[2 * cp + 1];
        #pragma unroll
        for (int d = 0; d < 16; ++d) {
            acc0 = fmaf(orow[d], wolT[d * 16 + 2 * cp], acc0);
            acc1 = fmaf(orow[d], wolT[d * 16 + 2 * cp + 1], acc1);
        }
        *reinterpret_cast<unsigned*>(
            A + bases[sq3] + (size_t)tok * tokStride + 2 * cp) =
            packbf2(acc0, acc1);
    }
}

// ---------------------------------------------------------------------------
// Kernel 5: out = hidden + conv(rest)
// ---------------------------------------------------------------------------
__global__ __launch_bounds__(256) void conv_out_kernel(
    const bf16* __restrict__ A, const float* __restrict__ hid,
    const float* __restrict__ pw, const float* __restrict__ pb,
    float* __restrict__ out)
{
    __shared__ float wl[9 * 256];
    __shared__ float bl[16];
    int t = threadIdx.x;
    {
        int ic = t >> 4, oc = t & 15;
        #pragma unroll
        for (int k = 0; k < 9; ++k)
            wl[k * 256 + t] = pw[(oc * 16 + ic) * 9 + k];
    }
    if (t < 16) bl[t] = pb[t];
    __syncthreads();

    int gid = blockIdx.x * 256 + t;   // 0 .. NIMG*PIX-1
    int wi = gid & 63, hi = (gid >> 6) & 63;
    int img = gid >> 12;
    const bf16* inp = A + ((size_t)img << 16);
    float acc[16];
    #pragma unroll
    for (int oc = 0; oc < 16; ++oc) acc[oc] = bl[oc];

    for (int ky = 0; ky < 3; ++ky) {
        int y = hi + ky - 1;
        if ((unsigned)y >= 64u) continue;
        for (int kx = 0; kx < 3; ++kx) {
            int x = wi + kx - 1;
            if ((unsigned)x >= 64u) continue;
            float xv[16];
            ld16bf(inp + (((y << 6) + x) << 4), xv);
            const float* wt = &wl[(ky * 3 + kx) * 256];
            #pragma unroll
            for (int ic = 0; ic < 16; ++ic) {
                #pragma unroll
                for (int oc = 0; oc < 16; ++oc)
                    acc[oc] = fmaf(xv[ic], wt[ic * 16 + oc], acc[oc]);
            }
        }
    }
    size_t off = ((size_t)gid) << 4;
    float hv[16];
    ld16f(hid + off, hv);
    float res[16];
    #pragma unroll
    for (int k = 0; k < 16; ++k) res[k] = acc[k] + hv[k];
    st16f(out + off, res);
}

// ---------------------------------------------------------------------------
extern "C" void kernel_launch(void* const* d_in, const int* in_sizes, int n_in,
                              void* d_out, int out_size, void* d_ws, size_t ws_size,
                              hipStream_t stream) {
    const float* hid  = (const float*)d_in[0];
    const float* ref  = (const float*)d_in[1];
    const float* emb  = (const float*)d_in[2];
    const float* ciw  = (const float*)d_in[3];
    const float* cib  = (const float*)d_in[4];
    const float* e1w  = (const float*)d_in[5];
    const float* e1b  = (const float*)d_in[6];
    const float* e2w  = (const float*)d_in[7];
    const float* e2b  = (const float*)d_in[8];
    const float* wqx  = (const float*)d_in[9];
    const float* wkx  = (const float*)d_in[10];
    const float* wvx  = (const float*)d_in[11];
    const float* wox  = (const float*)d_in[12];
    const float* box_ = (const float*)d_in[13];
    const float* wqy  = (const float*)d_in[14];
    const float* wky  = (const float*)d_in[15];
    const float* wvy  = (const float*)d_in[16];
    const float* woy  = (const float*)d_in[17];
    const float* boy  = (const float*)d_in[18];
    const float* wqt  = (const float*)d_in[19];
    const float* wkt  = (const float*)d_in[20];
    const float* wvt  = (const float*)d_in[21];
    const float* wot  = (const float*)d_in[22];
    const float* bot  = (const float*)d_in[23];
    const float* ng   = (const float*)d_in[24];
    const float* nb   = (const float*)d_in[25];
    const float* pjw  = (const float*)d_in[26];
    const float* pjb  = (const float*)d_in[27];

    bf16* A = (bf16*)d_ws;     // 4 MiB in workspace
    bf16* R = (bf16*)d_out;    // 4 MiB scratch inside the 8 MiB f32 output buf
                               // (fully overwritten by conv_out at the end)

    conv_in_kernel<<<(2 * NIMG * PIX) / 256, 256, 0, stream>>>(
        hid, ref, ciw, cib, emb, e1w, e1b, e2w, e2b, A, R);

    // Stage X: seq=(b,f,h), S=2W=128, token stride 16 (contiguous rows), TPT=2
    attn_kernel<128, 1, 8><<<BB * FF * HH, 256, 0, stream>>>(
        A, R, 1, WW * CC, 0, CC, wqx, wkx, wvx, wox, box_, ng, nb);
    // Stage Y: seq=(b,f,w), S=2H=128, tok stride W*C; 2 consecutive w, TPT=1
    attn_kernel<128, 2, 4><<<(BB * FF * WW) / 2, 256, 0, stream>>>(
        A, R, WW, IMGSZ, CC, WW * CC, wqy, wky, wvy, woy, boy, ng, nb);
    // Stage T: seq=(b,h,w), S=2F=32, tok stride H*W*C; 4 consecutive w, TPT=2
    attn_kernel<32, 4, 8><<<(BB * HH * WW) / 4, 256, 0, stream>>>(
        A, R, HH * WW, FF * IMGSZ, CC, IMGSZ, wqt, wkt, wvt, wot, bot, ng, nb);

    conv_out_kernel<<<(NIMG * PIX) / 256, 256, 0, stream>>>(A, hid, pjw, pjb, (float*)d_out);
}

// Round 3
// 243.095 us; speedup vs baseline: 1.1144x; 1.0282x over previous
//
#include <hip/hip_runtime.h>
#include <hip/hip_bf16.h>

typedef __hip_bfloat16 bf16;
// match the builtin's own return type (__fp16 ext_vector(2)) exactly
using hf2 = decltype(__builtin_amdgcn_cvt_pkrtz(0.f, 0.f));
typedef float f32x2 __attribute__((ext_vector_type(2)));

__device__ __forceinline__ float b2f(bf16 x) { return __bfloat162float(x); }

// ---------------------------------------------------------------------------
// Problem constants
// ---------------------------------------------------------------------------
#define BB   2
#define FF   16
#define HH   64
#define WW   64
#define CC   16     // in/out channels == MID
#define NIMG (BB*FF)        // 32
#define PIX  (HH*WW)        // 4096
#define IMGSZ (PIX*CC)      // 65536 elements per image (channel-last)

// scale(=1/sqrt(2)) * log2(e): folded into staged Wq; softmax uses raw v_exp_f32
#define QSCALE_LOG2E 1.0201394f

// ---- packed f16x2 helpers (v_cvt_pkrtz_f16_f32 / v_dot2_f32_f16) ----
__device__ __forceinline__ unsigned pkh2(float a, float b) {
    union { hf2 h; unsigned u; } x;
    x.h = __builtin_amdgcn_cvt_pkrtz(a, b);
    return x.u;
}
__device__ __forceinline__ float fdot2u(unsigned a, unsigned b, float c) {
    union { unsigned u; hf2 h; } A, B;
    A.u = a; B.u = b;
    return __builtin_amdgcn_fdot2(A.h, B.h, c, false);
}
__device__ __forceinline__ f32x2 f2(float a, float b) {
    f32x2 r; r.x = a; r.y = b; return r;
}

// ---- 16-element bf16 I/O (intermediates A/R) ----
__device__ __forceinline__ void ld16bf(const bf16* p, float* x) {
    const uint4* p4 = reinterpret_cast<const uint4*>(p);
    uint4 u0 = p4[0], u1 = p4[1];
    unsigned uu[8] = {u0.x, u0.y, u0.z, u0.w, u1.x, u1.y, u1.z, u1.w};
    #pragma unroll
    for (int k = 0; k < 8; ++k) {
        union { unsigned u; float f; } lo, hi;
        lo.u = uu[k] << 16;
        hi.u = uu[k] & 0xffff0000u;
        x[2 * k] = lo.f;
        x[2 * k + 1] = hi.f;
    }
}
__device__ __forceinline__ void st16bf(bf16* p, const float* x) {
    union { bf16 h[16]; uint4 u[2]; } o;
    #pragma unroll
    for (int k = 0; k < 16; ++k) o.h[k] = __float2bfloat16(x[k]);
    uint4* p4 = reinterpret_cast<uint4*>(p);
    p4[0] = o.u[0];
    p4[1] = o.u[1];
}

// ---- 16-element fp32 I/O (global inputs/outputs) ----
__device__ __forceinline__ void ld16f(const float* p, float* x) {
    const float4* p4 = reinterpret_cast<const float4*>(p);
    #pragma unroll
    for (int q = 0; q < 4; ++q) {
        float4 v = p4[q];
        x[4 * q] = v.x; x[4 * q + 1] = v.y; x[4 * q + 2] = v.z; x[4 * q + 3] = v.w;
    }
}
__device__ __forceinline__ void st16f(float* p, const float* x) {
    float4* p4 = reinterpret_cast<float4*>(p);
    #pragma unroll
    for (int q = 0; q < 4; ++q)
        p4[q] = make_float4(x[4 * q], x[4 * q + 1], x[4 * q + 2], x[4 * q + 3]);
}

__device__ __forceinline__ unsigned packbf2(float a, float b) {
    union { bf16 h[2]; unsigned u; } pk;
    pk.h[0] = __float2bfloat16(a);
    pk.h[1] = __float2bfloat16(b);
    return pk.u;
}

// ---------------------------------------------------------------------------
// Kernel 1: conv stem on hidden (->A) and ref (->R, + fused emb-MLP).
// MAC path: pixel packed to 8 f16x2, weights staged pre-packed f16x2 ->
// 8 pack + 128 fdot2 per tap (vs 256 fma + 256 ds_read).
// ---------------------------------------------------------------------------
__global__ __launch_bounds__(256) void conv_in_kernel(
    const float* __restrict__ hid, const float* __restrict__ ref,
    const float* __restrict__ cw, const float* __restrict__ cb,
    const float* __restrict__ emb,
    const float* __restrict__ e1w, const float* __restrict__ e1b,
    const float* __restrict__ e2w, const float* __restrict__ e2b,
    bf16* __restrict__ A, bf16* __restrict__ R)
{
    __shared__ unsigned w2l[9 * 128];   // [tap][oc][ic/2] f16x2
    __shared__ float bl[16];
    __shared__ float hl[16];
    __shared__ float el[16];
    int t = threadIdx.x;
    if (t < 128) {
        int oc = t & 15, c2 = t >> 4;
        #pragma unroll
        for (int k = 0; k < 9; ++k)
            w2l[k * 128 + oc * 8 + c2] =
                pkh2(cw[(oc * 16 + 2 * c2) * 9 + k],
                     cw[(oc * 16 + 2 * c2 + 1) * 9 + k]);
    }
    if (t < 16) bl[t] = cb[t];

    int gid  = blockIdx.x * 256 + t;       // 0 .. 2*NIMG*PIX-1
    int wi   = gid & 63;
    int hi   = (gid >> 6) & 63;
    int img2 = gid >> 12;                  // uniform per block (16 blocks/img)
    int isref = img2 >> 5;
    int img  = img2 & 31;
    int bi   = img >> 4;

    if (isref) {        // block-uniform branch: barriers inside are safe
        if (t < 16) {
            float acc = e1b[t];
            const float* er = emb + bi * 512;
            const float* wr = e1w + t * 512;
            for (int k = 0; k < 512; ++k) acc = fmaf(er[k], wr[k], acc);
            hl[t] = acc / (1.f + __expf(-acc));   // silu
        }
        __syncthreads();
        if (t < 16) {
            float acc = e2b[t];
            #pragma unroll
            for (int k = 0; k < 16; ++k) acc = fmaf(hl[k], e2w[t * 16 + k], acc);
            el[t] = acc;
        }
    }
    __syncthreads();

    const float* inp = (isref ? ref : hid) + (size_t)img * IMGSZ;
    float acc[16];
    #pragma unroll
    for (int oc = 0; oc < 16; ++oc)
        acc[oc] = bl[oc] + (isref ? el[oc] : 0.f);

    for (int ky = 0; ky < 3; ++ky) {
        int y = hi + ky - 1;
        if ((unsigned)y >= 64u) continue;
        for (int kx = 0; kx < 3; ++kx) {
            int x = wi + kx - 1;
            if ((unsigned)x >= 64u) continue;
            float xv[16];
            ld16f(inp + (((y << 6) + x) << 4), xv);
            unsigned xp[8];
            #pragma unroll
            for (int c2 = 0; c2 < 8; ++c2)
                xp[c2] = pkh2(xv[2 * c2], xv[2 * c2 + 1]);
            const unsigned* wt = &w2l[(ky * 3 + kx) * 128];
            #pragma unroll
            for (int oc = 0; oc < 16; ++oc) {
                float a = acc[oc];
                #pragma unroll
                for (int c2 = 0; c2 < 8; ++c2)
                    a = fdot2u(xp[c2], wt[oc * 8 + c2], a);
                acc[oc] = a;
            }
        }
    }
    bf16* op = (isref ? R : A) + ((size_t)(img * PIX + (hi << 6) + wi) << 4);
    st16bf(op, acc);
}

// ---------------------------------------------------------------------------
// Attention stage. 256 threads; TPT = 256/(SEQPB*S) threads per token (1 or 2).
// Sequence s: tokens j<S/2 from A, j>=S/2 from R.
//   token j elem offset = (s/d2)*str1 + (s%d2)*str2 + j*tokStride
// Output (first S/2 tokens) written in place into A (bf16); the T stage also
// writes an f16x2 shadow copy (A16) consumed by conv_out with zero unpack.
//
// Phase 2 uses packed-FP32 math: queries paired into f32x2 accumulators so
// softmax accumulation runs on v_pk_add_f32 / v_pk_fma_f32 (2 ops/issue).
// ---------------------------------------------------------------------------
template<int S, int SEQPB, int MINW, bool F16OUT>
__global__ __launch_bounds__(256, MINW) void attn_kernel(
    bf16* __restrict__ A, const bf16* __restrict__ R,
    unsigned* __restrict__ A16,
    int d2, int str1, int str2, int tokStride,
    const float* __restrict__ wq, const float* __restrict__ wk,
    const float* __restrict__ wv, const float* __restrict__ wo,
    const float* __restrict__ bo, const float* __restrict__ gw,
    const float* __restrict__ bw)
{
    constexpr int HS  = S / 2;             // queries per sequence
    constexpr int KQ  = S / 2;             // keys per phase-2 thread (parity)
    constexpr int TPT = 256 / (SEQPB * S); // threads per token: 1 or 2
    constexpr int NDIM = 16 / TPT;         // qkv dims per phase-1 thread
    constexpr int ITEMS = 256 / SEQPB;     // phase-2 threads per sequence
    constexpr int NQG = ITEMS / 16;        // query groups per sequence
    constexpr int QB  = HS / NQG;          // queries per phase-2 thread
    constexpr int QP  = QB / 2;            // query PAIRS per phase-2 thread
    constexpr int KROW = 10;               // k/v/q token row stride (uints)
    constexpr int QROW = 20;               // o row stride (floats)
    constexpr int LSQ = (SEQPB == 1) ? 0 : ((SEQPB == 2) ? 1 : 2);
    constexpr int NW3 = SEQPB * HS * 8 / 256;  // phase-3 reps

    __shared__ float wolT[256];
    __shared__ unsigned wq2L[128], wk2L[128], wv2L[128];   // f16x2-packed rows
    __shared__ float bol[16], gl[16], blw[16];
    __shared__ __align__(16) unsigned kU[SEQPB * S * KROW];   // k f16x2; o (f32, stride 20) after barrier
    __shared__ __align__(16) unsigned vU[SEQPB * S * KROW];   // v bf16x2
    __shared__ __align__(16) unsigned qL[SEQPB * HS * KROW];  // q f16x2 (scaled)
    __shared__ int bases[SEQPB];

    int t = threadIdx.x;
    wolT[(t & 15) * 16 + (t >> 4)] = wo[t];   // transposed: [d][c]
    if (t < 128) {
        // pack weight rows [d][c] -> [d][c/2] f16x2; wq pre-scaled
        float2 qw = reinterpret_cast<const float2*>(wq)[t];
        float2 kw = reinterpret_cast<const float2*>(wk)[t];
        float2 vw = reinterpret_cast<const float2*>(wv)[t];
        wq2L[t] = pkh2(qw.x * QSCALE_LOG2E, qw.y * QSCALE_LOG2E);
        wk2L[t] = pkh2(kw.x, kw.y);
        wv2L[t] = pkh2(vw.x, vw.y);
    }
    if (t < 16) { bol[t] = bo[t]; gl[t] = gw[t]; blw[t] = bw[t]; }
    if (t < SEQPB) {
        int seq = blockIdx.x * SEQPB + t;
        bases[t] = (seq / d2) * str1 + (seq % d2) * str2;
    }
    __syncthreads();

    // ---- phase 1: token load, +posembed, LayerNorm, QKV (fdot2) -> LDS ----
    {
        int tokIdx = (TPT == 2) ? (t >> 1) : t;
        int db     = (TPT == 2) ? ((t & 1) * 8) : 0;
        int sq = tokIdx & (SEQPB - 1);     // sq fastest: adjacent lanes coalesce
        int i  = tokIdx >> LSQ;
        const bf16* src = (i < HS)
            ? (A + bases[sq] + (size_t)i * tokStride)
            : (R + bases[sq] + (size_t)(i - HS) * tokStride);
        float x[16];
        ld16bf(src, x);
        const float om[8] = {1.f, 0.31622776601683794f, 0.1f, 0.031622776601683794f,
                             0.01f, 0.0031622776601683794f, 0.001f, 0.00031622776601683794f};
        float fi = (float)i;
        #pragma unroll
        for (int k = 0; k < 8; ++k) {
            float sv, cv;
            __sincosf(fi * om[k], &sv, &cv);
            x[k]     += sv;
            x[k + 8] += cv;
        }
        float m = 0.f;
        #pragma unroll
        for (int c = 0; c < 16; ++c) m += x[c];
        m *= (1.f / 16.f);
        float var = 0.f;
        #pragma unroll
        for (int c = 0; c < 16; ++c) { float d = x[c] - m; var = fmaf(d, d, var); }
        var *= (1.f / 16.f);
        float rs = rsqrtf(var + 1e-5f);
        float xn[16];
        #pragma unroll
        for (int c = 0; c < 16; ++c) xn[c] = (x[c] - m) * rs * gl[c] + blw[c];

        // pack normalized token once; all three projections become dot2 chains
        unsigned xp[8];
        #pragma unroll
        for (int c2 = 0; c2 < 8; ++c2) xp[c2] = pkh2(xn[2 * c2], xn[2 * c2 + 1]);

        float qv[NDIM], kv[NDIM], vv[NDIM];
        #pragma unroll
        for (int dd = 0; dd < NDIM; ++dd) {
            int d = db + dd;
            float aq = 0.f, ak = 0.f, av = 0.f;
            #pragma unroll
            for (int c2 = 0; c2 < 8; ++c2) {
                aq = fdot2u(xp[c2], wq2L[d * 8 + c2], aq);
                ak = fdot2u(xp[c2], wk2L[d * 8 + c2], ak);
                av = fdot2u(xp[c2], wv2L[d * 8 + c2], av);
            }
            qv[dd] = aq; kv[dd] = ak; vv[dd] = av;
        }
        int row = (sq * S + i) * KROW + (db >> 1);   // uint index, even
        uint2* kr = reinterpret_cast<uint2*>(&kU[row]);
        uint2* vr = reinterpret_cast<uint2*>(&vU[row]);
        #pragma unroll
        for (int e = 0; e < NDIM / 4; ++e) {
            kr[e] = make_uint2(pkh2(kv[4 * e], kv[4 * e + 1]),
                               pkh2(kv[4 * e + 2], kv[4 * e + 3]));
            vr[e] = make_uint2(packbf2(vv[4 * e], vv[4 * e + 1]),
                               packbf2(vv[4 * e + 2], vv[4 * e + 3]));
        }
        if (i < HS) {
            uint2* qr = reinterpret_cast<uint2*>(&qL[(sq * HS + i) * KROW + (db >> 1)]);
            #pragma unroll
            for (int e = 0; e < NDIM / 4; ++e)
                qr[e] = make_uint2(pkh2(qv[4 * e], qv[4 * e + 1]),
                                   pkh2(qv[4 * e + 2], qv[4 * e + 3]));
        }
    }
    __syncthreads();

    // ---- phase 2: single-pass softmax (exp2 domain), parity key split,
    //      query-paired packed-FP32 accumulation ----
    int sq2 = t / ITEMS;
    int r   = t % ITEMS;
    int qg  = r >> 4;          // query group (QB queries)
    int hd  = (r >> 1) & 7;    // head
    int half = r & 1;          // key parity
    float* oL = reinterpret_cast<float*>(kU);   // overlay after barrier
    {
        unsigned q2[QB];
        f32x2 l2[QP], a0p[QP], a1p[QP];
        #pragma unroll
        for (int qq = 0; qq < QB; ++qq)
            q2[qq] = qL[(sq2 * HS + qg * QB + qq) * KROW + hd];  // scaled f16x2
        #pragma unroll
        for (int m = 0; m < QP; ++m) {
            l2[m] = f2(0.f, 0.f); a0p[m] = f2(0.f, 0.f); a1p[m] = f2(0.f, 0.f);
        }
        const unsigned* kp = &kU[(sq2 * S + half) * KROW + hd];
        const unsigned* vp = &vU[(sq2 * S + half) * KROW + hd];
        #pragma unroll 8
        for (int jj = 0; jj < KQ; ++jj) {            // key j = 2*jj + half
            unsigned ku = kp[jj * 2 * KROW];
            unsigned vu = vp[jj * 2 * KROW];
            union { unsigned u; float f; } v0, v1;
            v0.u = vu << 16; v1.u = vu & 0xffff0000u;
            f32x2 v00 = f2(v0.f, v0.f);
            f32x2 v11 = f2(v1.f, v1.f);
            #pragma unroll
            for (int m = 0; m < QP; ++m) {
                f32x2 p2;
                p2.x = __builtin_amdgcn_exp2f(fdot2u(q2[2 * m], ku, 0.f));
                p2.y = __builtin_amdgcn_exp2f(fdot2u(q2[2 * m + 1], ku, 0.f));
                l2[m] += p2;                                    // v_pk_add_f32
                a0p[m] = __builtin_elementwise_fma(p2, v00, a0p[m]);  // v_pk_fma_f32
                a1p[m] = __builtin_elementwise_fma(p2, v11, a1p[m]);
            }
        }
        #pragma unroll
        for (int m = 0; m < QP; ++m) {
            l2[m].x  += __shfl_xor(l2[m].x, 1);  l2[m].y  += __shfl_xor(l2[m].y, 1);
            a0p[m].x += __shfl_xor(a0p[m].x, 1); a0p[m].y += __shfl_xor(a0p[m].y, 1);
            a1p[m].x += __shfl_xor(a1p[m].x, 1); a1p[m].y += __shfl_xor(a1p[m].y, 1);
        }
        __syncthreads();   // all k/q reads done in every thread; kU reusable as oL
        if (half == 0) {
            #pragma unroll
            for (int m = 0; m < QP; ++m) {
                float inv0 = 1.f / l2[m].x;
                float inv1 = 1.f / l2[m].y;
                *reinterpret_cast<float2*>(
                    &oL[(sq2 * HS + qg * QB + 2 * m) * QROW + 2 * hd]) =
                    make_float2(a0p[m].x * inv0, a1p[m].x * inv0);
                *reinterpret_cast<float2*>(
                    &oL[(sq2 * HS + qg * QB + 2 * m + 1) * QROW + 2 * hd]) =
                    make_float2(a0p[m].y * inv1, a1p[m].y * inv1);
            }
        }
    }
    __syncthreads();

    // ---- phase 3: out-proj, in-place bf16x2 write; sq fastest for lines ----
    #pragma unroll
    for (int rep = 0; rep < NW3; ++rep) {
        int idx = t + rep * 256;          // < SEQPB*HS*8
        int cp  = idx & 7;                // channel pair
        int g   = idx >> 3;
        int sq3 = g & (SEQPB - 1);
        int tok = g >> LSQ;
        const float* orow = &oL[(sq3 * HS + tok) * QROW];
        float acc0 = bol[2 * cp], acc1 = bol[2 * cp + 1];
        #pragma unroll
        for (int d = 0; d < 16; ++d) {
            acc0 = fmaf(orow[d], wolT[d * 16 + 2 * cp], acc0);
            acc1 = fmaf(orow[d], wolT[d * 16 + 2 * cp + 1], acc1);
        }
        int off = bases[sq3] + tok * tokStride;
        *reinterpret_cast<unsigned*>(A + off + 2 * cp) = packbf2(acc0, acc1);
        if constexpr (F16OUT)
            A16[(off >> 1) + cp] = pkh2(acc0, acc1);   // f16 shadow for conv_out
    }
}

// ---------------------------------------------------------------------------
// Kernel 5: out = hidden + conv(rest).  Input is the f16x2 shadow written by
// the T attention stage: operands feed fdot2 directly, zero unpack.
// ---------------------------------------------------------------------------
__global__ __launch_bounds__(256) void conv_out_kernel(
    const unsigned* __restrict__ A16, const float* __restrict__ hid,
    const float* __restrict__ pw, const float* __restrict__ pb,
    float* __restrict__ out)
{
    __shared__ unsigned w2l[9 * 128];   // [tap][oc][ic/2] f16x2
    __shared__ float bl[16];
    int t = threadIdx.x;
    if (t < 128) {
        int oc = t & 15, c2 = t >> 4;
        #pragma unroll
        for (int k = 0; k < 9; ++k)
            w2l[k * 128 + oc * 8 + c2] =
                pkh2(pw[(oc * 16 + 2 * c2) * 9 + k],
                     pw[(oc * 16 + 2 * c2 + 1) * 9 + k]);
    }
    if (t < 16) bl[t] = pb[t];
    __syncthreads();

    int gid = blockIdx.x * 256 + t;   // 0 .. NIMG*PIX-1
    int wi = gid & 63, hi = (gid >> 6) & 63;
    int img = gid >> 12;
    const unsigned* inp = A16 + ((size_t)img << 15);   // 32768 uints / image
    float acc[16];
    #pragma unroll
    for (int oc = 0; oc < 16; ++oc) acc[oc] = bl[oc];

    for (int ky = 0; ky < 3; ++ky) {
        int y = hi + ky - 1;
        if ((unsigned)y >= 64u) continue;
        for (int kx = 0; kx < 3; ++kx) {
            int x = wi + kx - 1;
            if ((unsigned)x >= 64u) continue;
            const uint4* p4 = reinterpret_cast<const uint4*>(
                inp + (((y << 6) + x) << 3));           // 8 uints / pixel
            uint4 u0 = p4[0], u1 = p4[1];
            unsigned xp[8] = {u0.x, u0.y, u0.z, u0.w, u1.x, u1.y, u1.z, u1.w};
            const unsigned* wt = &w2l[(ky * 3 + kx) * 128];
            #pragma unroll
            for (int oc = 0; oc < 16; ++oc) {
                float a = acc[oc];
                #pragma unroll
                for (int c2 = 0; c2 < 8; ++c2)
                    a = fdot2u(xp[c2], wt[oc * 8 + c2], a);
                acc[oc] = a;
            }
        }
    }
    size_t off = ((size_t)gid) << 4;
    float hv[16];
    ld16f(hid + off, hv);
    float res[16];
    #pragma unroll
    for (int k = 0; k < 16; ++k) res[k] = acc[k] + hv[k];
    st16f(out + off, res);
}

// ---------------------------------------------------------------------------
extern "C" void kernel_launch(void* const* d_in, const int* in_sizes, int n_in,
                              void* d_out, int out_size, void* d_ws, size_t ws_size,
                              hipStream_t stream) {
    const float* hid  = (const float*)d_in[0];
    const float* ref  = (const float*)d_in[1];
    const float* emb  = (const float*)d_in[2];
    const float* ciw  = (const float*)d_in[3];
    const float* cib  = (const float*)d_in[4];
    const float* e1w  = (const float*)d_in[5];
    const float* e1b  = (const float*)d_in[6];
    const float* e2w  = (const float*)d_in[7];
    const float* e2b  = (const float*)d_in[8];
    const float* wqx  = (const float*)d_in[9];
    const float* wkx  = (const float*)d_in[10];
    const float* wvx  = (const float*)d_in[11];
    const float* wox  = (const float*)d_in[12];
    const float* box_ = (const float*)d_in[13];
    const float* wqy  = (const float*)d_in[14];
    const float* wky  = (const float*)d_in[15];
    const float* wvy  = (const float*)d_in[16];
    const float* woy  = (const float*)d_in[17];
    const float* boy  = (const float*)d_in[18];
    const float* wqt  = (const float*)d_in[19];
    const float* wkt  = (const float*)d_in[20];
    const float* wvt  = (const float*)d_in[21];
    const float* wot  = (const float*)d_in[22];
    const float* bot  = (const float*)d_in[23];
    const float* ng   = (const float*)d_in[24];
    const float* nb   = (const float*)d_in[25];
    const float* pjw  = (const float*)d_in[26];
    const float* pjb  = (const float*)d_in[27];

    bf16* A = (bf16*)d_ws;     // 4 MiB in workspace
    unsigned* A16 = (unsigned*)((char*)d_ws + (4 << 20));  // 4 MiB f16 shadow
    bf16* R = (bf16*)d_out;    // 4 MiB scratch inside the 8 MiB f32 output buf
                               // (fully overwritten by conv_out at the end)

    conv_in_kernel<<<(2 * NIMG * PIX) / 256, 256, 0, stream>>>(
        hid, ref, ciw, cib, emb, e1w, e1b, e2w, e2b, A, R);

    // Stage X: seq=(b,f,h), S=2W=128, token stride 16 (contiguous rows), TPT=2
    attn_kernel<128, 1, 8, false><<<BB * FF * HH, 256, 0, stream>>>(
        A, R, nullptr, 1, WW * CC, 0, CC, wqx, wkx, wvx, wox, box_, ng, nb);
    // Stage Y: seq=(b,f,w), S=2H=128, tok stride W*C; 2 consecutive w, TPT=1
    attn_kernel<128, 2, 4, false><<<(BB * FF * WW) / 2, 256, 0, stream>>>(
        A, R, nullptr, WW, IMGSZ, CC, WW * CC, wqy, wky, wvy, woy, boy, ng, nb);
    // Stage T: seq=(b,h,w), S=2F=32, tok stride H*W*C; 4 consecutive w, TPT=2
    // writes bf16 A (unused afterwards) + f16 shadow A16 for conv_out
    attn_kernel<32, 4, 8, true><<<(BB * HH * WW) / 4, 256, 0, stream>>>(
        A, R, A16, HH * WW, FF * IMGSZ, CC, IMGSZ, wqt, wkt, wvt, wot, bot, ng, nb);

    conv_out_kernel<<<(NIMG * PIX) / 256, 256, 0, stream>>>(A16, hid, pjw, pjb, (float*)d_out);
}